// Round 1
// 1261.703 us; speedup vs baseline: 1.7503x; 1.7503x over previous
//
#include <hip/hip_runtime.h>
#include <math.h>

// Problem constants (MultiviewCrossAttnFeature)
#define NVOX 50000
#define MV   12
#define FD   256
#define AUGD 272   // FD + 16 extrinsics
#define BQ   16384
#define HN   8
#define DKC  64
#define HD   512   // HN*DKC
#define PEO  8
#define G    4     // queries per block

// ---------------- min/max over voxels (N,3), fp32 ----------------
__global__ void kmm_part(const float* __restrict__ vox, float* __restrict__ part) {
    int tid = threadIdx.x;
    float mn[3] = {1e30f, 1e30f, 1e30f};
    float mx[3] = {-1e30f, -1e30f, -1e30f};
    for (int i = blockIdx.x * 256 + tid; i < NVOX; i += 64 * 256) {
        #pragma unroll
        for (int c = 0; c < 3; ++c) {
            float v = vox[3 * i + c];
            mn[c] = fminf(mn[c], v);
            mx[c] = fmaxf(mx[c], v);
        }
    }
    #pragma unroll
    for (int s = 1; s < 64; s <<= 1) {
        #pragma unroll
        for (int c = 0; c < 3; ++c) {
            mn[c] = fminf(mn[c], __shfl_xor(mn[c], s, 64));
            mx[c] = fmaxf(mx[c], __shfl_xor(mx[c], s, 64));
        }
    }
    __shared__ float smn[4][3], smx[4][3];
    int w = tid >> 6;
    if ((tid & 63) == 0) {
        #pragma unroll
        for (int c = 0; c < 3; ++c) { smn[w][c] = mn[c]; smx[w][c] = mx[c]; }
    }
    __syncthreads();
    if (tid == 0) {
        #pragma unroll
        for (int c = 0; c < 3; ++c) {
            float a = fminf(fminf(smn[0][c], smn[1][c]), fminf(smn[2][c], smn[3][c]));
            float b = fmaxf(fmaxf(smx[0][c], smx[1][c]), fmaxf(smx[2][c], smx[3][c]));
            part[blockIdx.x * 6 + c] = a;
            part[blockIdx.x * 6 + 3 + c] = b;
        }
    }
}

__global__ void kmm_final(const float* __restrict__ part, float* __restrict__ mm) {
    int t = threadIdx.x;  // 64 threads = 1 wave
    float mn[3], mx[3];
    #pragma unroll
    for (int c = 0; c < 3; ++c) { mn[c] = part[t * 6 + c]; mx[c] = part[t * 6 + 3 + c]; }
    #pragma unroll
    for (int s = 1; s < 64; s <<= 1) {
        #pragma unroll
        for (int c = 0; c < 3; ++c) {
            mn[c] = fminf(mn[c], __shfl_xor(mn[c], s, 64));
            mx[c] = fmaxf(mx[c], __shfl_xor(mx[c], s, 64));
        }
    }
    if (t == 0) {
        #pragma unroll
        for (int c = 0; c < 3; ++c) { mm[c] = mn[c]; mm[3 + c] = mx[c]; }
    }
}

// ---------------- main fused kernel: G=4 query voxels / block ----------------
// Reassociated attention: never materialize K or V.
//   qW[g][h][t]  = sum_d q[g][h][d] * Wk[t][h*64+d]          (B)
//   logit[g,h,m] = sum_t aug[g][m][t] * qW[g][h][t]           (C)
//   p = softmax_m(logit*0.125 + mask)                          (D)
//   pf[g][h][t]  = sum_m p[g][m][h] * feat[g][m][t]           (E)
//   out[g][h*64+dv] = sum_t pf[g][h][t] * Wv[t][h*64+dv]      (F)
__global__ __launch_bounds__(256) void kattn(
    const int* __restrict__ vi, const float* __restrict__ voxels,
    const float* __restrict__ feats, const float* __restrict__ scores,
    const int* __restrict__ cams, const float* __restrict__ extr,
    const float* __restrict__ Wq, const float* __restrict__ Wk, const float* __restrict__ Wv,
    const float* __restrict__ mm, float* __restrict__ out)
{
    // padded strides chosen for 16B alignment + bank spread:
    // q_s head stride 68 (68%32=4 -> heads land on distinct bank quads)
    // qWpf head stride 280 (16B-aligned, reused as qW then pf)
    __shared__ float q_s[G][HN][68];
    __shared__ float qWpf[G][HN][280];
    __shared__ float lp_s[G][MV][HN];      // logits, then probabilities
    __shared__ float ext_s[G][MV][16];
    __shared__ float pe_s[G][24];
    __shared__ float mask_s[G][MV];

    const int tid = threadIdx.x;
    const int b0 = blockIdx.x * G;

    // ---- A: stage pe, mask, extrinsics ----
    if (tid < G * 24) {
        int g = tid / 24, t = tid % 24;
        int idx = vi[b0 + g];
        int p = t / 3, c = t % 3;
        float vmn = mm[c], vmx = mm[3 + c];
        float x = (voxels[idx * 3 + c] - vmn) / (vmx - vmn) - 0.5f;
        pe_s[g][t] = sinf(x * (float)(1 << p));
    }
    if (tid < G * MV) {
        int g = tid / MV, m = tid % MV;
        int idx = vi[b0 + g];
        mask_s[g][m] = (scores[idx * MV + m] < 0.0f) ? -1e30f : 0.0f;
    }
    for (int e = tid; e < G * MV * 16; e += 256) {
        int g = e / (MV * 16), r = e % (MV * 16);
        int m = r >> 4, c = r & 15;
        int idx = vi[b0 + g];
        int cam = cams[idx * MV + m];
        ext_s[g][m][c] = extr[cam * 16 + c];
    }
    __syncthreads();

    // ---- A2: Q projection. Thread j -> q columns (2j, 2j+1) ----
    {
        const float2* Wq2 = (const float2*)Wq;   // row stride 256 float2
        float2 w[24];
        #pragma unroll
        for (int t = 0; t < 24; ++t) w[t] = Wq2[t * 256 + tid];
        int h = tid >> 5, d2 = (tid & 31) * 2;
        #pragma unroll
        for (int g = 0; g < G; ++g) {
            float q0 = 0.f, q1 = 0.f;
            #pragma unroll
            for (int t = 0; t < 24; ++t) {
                float p = pe_s[g][t];
                q0 = fmaf(p, w[t].x, q0);
                q1 = fmaf(p, w[t].y, q1);
            }
            *(float2*)&q_s[g][h][d2] = make_float2(q0, q1);
        }
    }
    __syncthreads();

    // ---- B: qW = q @ Wk^T  (streams Wk once per block, reused for G queries) ----
    {
        int h = tid & 7, tq = tid >> 3;   // tq in 0..31, owns t-quads
        for (int pass = 0; pass < 3; ++pass) {
            int tbase = (pass * 32 + tq) * 4;
            if (tbase < AUGD) {
                float acc[G][4];
                #pragma unroll
                for (int g = 0; g < G; ++g)
                    #pragma unroll
                    for (int r = 0; r < 4; ++r) acc[g][r] = 0.f;
                const float* wkb = Wk + (size_t)tbase * HD + h * 64;
                #pragma unroll 4
                for (int d4 = 0; d4 < 16; ++d4) {
                    float4 wk0 = *(const float4*)(wkb + 0 * HD + d4 * 4);
                    float4 wk1 = *(const float4*)(wkb + 1 * HD + d4 * 4);
                    float4 wk2 = *(const float4*)(wkb + 2 * HD + d4 * 4);
                    float4 wk3 = *(const float4*)(wkb + 3 * HD + d4 * 4);
                    #pragma unroll
                    for (int g = 0; g < G; ++g) {
                        float4 qv = *(const float4*)&q_s[g][h][d4 * 4];  // broadcast per h-group
                        acc[g][0] += qv.x*wk0.x + qv.y*wk0.y + qv.z*wk0.z + qv.w*wk0.w;
                        acc[g][1] += qv.x*wk1.x + qv.y*wk1.y + qv.z*wk1.z + qv.w*wk1.w;
                        acc[g][2] += qv.x*wk2.x + qv.y*wk2.y + qv.z*wk2.z + qv.w*wk2.w;
                        acc[g][3] += qv.x*wk3.x + qv.y*wk3.y + qv.z*wk3.z + qv.w*wk3.w;
                    }
                }
                #pragma unroll
                for (int g = 0; g < G; ++g)
                    *(float4*)&qWpf[g][h][tbase] =
                        make_float4(acc[g][0], acc[g][1], acc[g][2], acc[g][3]);
            }
        }
    }
    __syncthreads();

    // ---- C: logits. 768 partials = (g,m,h,half), 3 per thread ----
    {
        #pragma unroll
        for (int k = 0; k < 3; ++k) {
            int id = tid + k * 256;
            int half = id & 1;
            int h = (id >> 1) & 7;
            int gm = id >> 4;            // 0..47
            int m = gm % MV;
            int g = gm / MV;
            int idx = vi[b0 + g];
            const float4* fr = (const float4*)(feats + (size_t)idx * (MV * FD) + m * FD);
            const float4* qw = (const float4*)&qWpf[g][h][0];
            const float4* fr4 = fr + half * 32;
            const float4* qw4 = qw + half * 32;
            float acc = 0.f;
            #pragma unroll 8
            for (int i = 0; i < 32; ++i) {
                float4 f = fr4[i];
                float4 w = qw4[i];
                acc += f.x*w.x + f.y*w.y + f.z*w.z + f.w*w.w;
            }
            if (half) {  // extrinsics tail: aug t = 256..271
                const float4* er = (const float4*)&ext_s[g][m][0];
                #pragma unroll
                for (int e4 = 0; e4 < 4; ++e4) {
                    float4 f = er[e4];
                    float4 w = qw[64 + e4];
                    acc += f.x*w.x + f.y*w.y + f.z*w.z + f.w*w.w;
                }
            }
            acc += __shfl_xor(acc, 1, 64);   // combine halves (adjacent lanes)
            if (half == 0) lp_s[g][m][h] = acc * 0.125f + mask_s[g][m];
        }
    }
    __syncthreads();

    // ---- D: masked softmax over views, one (g,h) per thread ----
    if (tid < G * HN) {
        int g = tid >> 3, h = tid & 7;
        float l[MV], mx = -1e30f;
        #pragma unroll
        for (int m = 0; m < MV; ++m) { l[m] = lp_s[g][m][h]; mx = fmaxf(mx, l[m]); }
        float s = 0.f;
        #pragma unroll
        for (int m = 0; m < MV; ++m) { l[m] = __expf(l[m] - mx); s += l[m]; }
        float inv = 1.0f / s;
        #pragma unroll
        for (int m = 0; m < MV; ++m) lp_s[g][m][h] = l[m] * inv;
    }
    __syncthreads();

    // ---- E: pf = p @ feat. Thread (g, to) owns t-quad to for all 8 heads ----
    {
        int g = tid >> 6, to = tid & 63;
        int idx = vi[b0 + g];
        const float4* fr = (const float4*)(feats + (size_t)idx * (MV * FD));
        float acc[HN][4];
        #pragma unroll
        for (int h = 0; h < HN; ++h)
            #pragma unroll
            for (int r = 0; r < 4; ++r) acc[h][r] = 0.f;
        #pragma unroll 4
        for (int m = 0; m < MV; ++m) {
            float4 f  = fr[m * 64 + to];                      // coalesced
            float4 p0 = *(const float4*)&lp_s[g][m][0];       // broadcast
            float4 p1 = *(const float4*)&lp_s[g][m][4];
            acc[0][0] = fmaf(p0.x, f.x, acc[0][0]); acc[0][1] = fmaf(p0.x, f.y, acc[0][1]);
            acc[0][2] = fmaf(p0.x, f.z, acc[0][2]); acc[0][3] = fmaf(p0.x, f.w, acc[0][3]);
            acc[1][0] = fmaf(p0.y, f.x, acc[1][0]); acc[1][1] = fmaf(p0.y, f.y, acc[1][1]);
            acc[1][2] = fmaf(p0.y, f.z, acc[1][2]); acc[1][3] = fmaf(p0.y, f.w, acc[1][3]);
            acc[2][0] = fmaf(p0.z, f.x, acc[2][0]); acc[2][1] = fmaf(p0.z, f.y, acc[2][1]);
            acc[2][2] = fmaf(p0.z, f.z, acc[2][2]); acc[2][3] = fmaf(p0.z, f.w, acc[2][3]);
            acc[3][0] = fmaf(p0.w, f.x, acc[3][0]); acc[3][1] = fmaf(p0.w, f.y, acc[3][1]);
            acc[3][2] = fmaf(p0.w, f.z, acc[3][2]); acc[3][3] = fmaf(p0.w, f.w, acc[3][3]);
            acc[4][0] = fmaf(p1.x, f.x, acc[4][0]); acc[4][1] = fmaf(p1.x, f.y, acc[4][1]);
            acc[4][2] = fmaf(p1.x, f.z, acc[4][2]); acc[4][3] = fmaf(p1.x, f.w, acc[4][3]);
            acc[5][0] = fmaf(p1.y, f.x, acc[5][0]); acc[5][1] = fmaf(p1.y, f.y, acc[5][1]);
            acc[5][2] = fmaf(p1.y, f.z, acc[5][2]); acc[5][3] = fmaf(p1.y, f.w, acc[5][3]);
            acc[6][0] = fmaf(p1.z, f.x, acc[6][0]); acc[6][1] = fmaf(p1.z, f.y, acc[6][1]);
            acc[6][2] = fmaf(p1.z, f.z, acc[6][2]); acc[6][3] = fmaf(p1.z, f.w, acc[6][3]);
            acc[7][0] = fmaf(p1.w, f.x, acc[7][0]); acc[7][1] = fmaf(p1.w, f.y, acc[7][1]);
            acc[7][2] = fmaf(p1.w, f.z, acc[7][2]); acc[7][3] = fmaf(p1.w, f.w, acc[7][3]);
        }
        #pragma unroll
        for (int h = 0; h < HN; ++h)
            *(float4*)&qWpf[g][h][to * 4] =
                make_float4(acc[h][0], acc[h][1], acc[h][2], acc[h][3]);
    }
    __syncthreads();

    // ---- F: out = pf @ Wv. Thread j -> output cols (2j, 2j+1) for all g ----
    {
        const float2* Wv2 = (const float2*)Wv;   // row stride 256 float2
        int h = tid >> 5;
        float o[G][2];
        #pragma unroll
        for (int g = 0; g < G; ++g) { o[g][0] = 0.f; o[g][1] = 0.f; }
        #pragma unroll 4
        for (int t4 = 0; t4 < 64; ++t4) {
            float2 w0 = Wv2[(t4 * 4 + 0) * 256 + tid];
            float2 w1 = Wv2[(t4 * 4 + 1) * 256 + tid];
            float2 w2 = Wv2[(t4 * 4 + 2) * 256 + tid];
            float2 w3 = Wv2[(t4 * 4 + 3) * 256 + tid];
            #pragma unroll
            for (int g = 0; g < G; ++g) {
                float4 pf = *(const float4*)&qWpf[g][h][t4 * 4];  // broadcast per half-wave
                o[g][0] = fmaf(pf.x, w0.x, o[g][0]); o[g][0] = fmaf(pf.y, w1.x, o[g][0]);
                o[g][0] = fmaf(pf.z, w2.x, o[g][0]); o[g][0] = fmaf(pf.w, w3.x, o[g][0]);
                o[g][1] = fmaf(pf.x, w0.y, o[g][1]); o[g][1] = fmaf(pf.y, w1.y, o[g][1]);
                o[g][1] = fmaf(pf.z, w2.y, o[g][1]); o[g][1] = fmaf(pf.w, w3.y, o[g][1]);
            }
        }
        #pragma unroll
        for (int g = 0; g < G; ++g)
            ((float2*)out)[(size_t)(b0 + g) * (HD / 2) + tid] = make_float2(o[g][0], o[g][1]);
    }
}

extern "C" void kernel_launch(void* const* d_in, const int* in_sizes, int n_in,
                              void* d_out, int out_size, void* d_ws, size_t ws_size,
                              hipStream_t stream) {
    const int*   vi      = (const int*)d_in[0];
    const float* voxels  = (const float*)d_in[1];
    const float* feats   = (const float*)d_in[2];
    const float* scores  = (const float*)d_in[3];
    const int*   cams    = (const int*)d_in[4];
    const float* extr    = (const float*)d_in[5];
    const float* Wq      = (const float*)d_in[6];
    const float* Wk      = (const float*)d_in[7];
    const float* Wv      = (const float*)d_in[8];
    float* out = (float*)d_out;

    float* ws   = (float*)d_ws;
    float* mm   = ws;        // 6 floats: vmin[3], vmax[3]
    float* part = ws + 8;    // 64 * 6 partials

    kmm_part<<<64, 256, 0, stream>>>(voxels, part);
    kmm_final<<<1, 64, 0, stream>>>(part, mm);
    kattn<<<BQ / G, 256, 0, stream>>>(vi, voxels, feats, scores, cams, extr, Wq, Wk, Wv, mm, out);
}